// Round 19
// baseline (126.479 us; speedup 1.0000x reference)
//
#include <hip/hip_runtime.h>
#include <hip/hip_bf16.h>

// Swin window attention, fully fused, bf16-MFMA.
// Base = round-18 (117.1 us): R14 structure + weight de-dup through LDS.
// Round-19 single change: ASYNC weight staging via global_load_lds DMA with
// 1-tile (4 KB) double-buffer. R18's staging was serial (load->wait->ds_write
// ->barrier = ~200-400 cyc exposed x16 chunks). Now tile nt+1's DMA is issued
// at the top of iteration nt into the other half-buffer; its latency hides
// under tile nt's ds_reads+MFMAs+stores; the trailing __syncthreads (full
// vmcnt drain -- race-free by construction) lands it collectively. Phase-3
// tile-0 DMA is issued BEFORE phase 2 -> covered by the whole attention phase.
// Barrier count unchanged (24 + 8); reg round-trip eliminated.
// MFMA 16x16x32 bf16 layouts (validated end-to-end rounds 3/5/6/8):
//   src0 A: lane holds A[lane&15][(lane>>4)*8+j]
//   src1 B: lane holds B[(lane>>4)*8+j][lane&15]
//   D:      lane holds D[(lane>>4)*4+r][lane&15]

typedef __attribute__((ext_vector_type(8))) short bf16x8;
typedef __attribute__((ext_vector_type(4))) float f32x4;
typedef unsigned long long ull;

#define NTOK  49
#define CDIM  128
#define NWIN  256
#define SCALE 0.17677669529663687f
#define PROJ_WOFF 49152            // shorts: 96 frags * 512
#define WB_BYTES  131072

static __device__ __forceinline__ unsigned pk2(float a, float b) {
    __hip_bfloat162 h = __float22bfloat162_rn(make_float2(a, b));  // low = a, high = b, RNE
    unsigned u; __builtin_memcpy(&u, &h, 4); return u;
}
static __device__ __forceinline__ short bf1(float a) {
    __hip_bfloat16 h = __float2bfloat16(a);
    unsigned short u; __builtin_memcpy(&u, &h, 2); return (short)u;
}
// 16B-per-lane global->LDS DMA. ldst must be the WAVE-UNIFORM base; HW adds
// lane*16 (m104 semantics). gsrc is per-lane.
static __device__ __forceinline__ void gll16(const short* gsrc, short* ldst) {
    __builtin_amdgcn_global_load_lds(
        (const __attribute__((address_space(1))) unsigned*)(const void*)gsrc,
        (__attribute__((address_space(3))) unsigned*)(void*)ldst,
        16, 0, 0);
}
static __device__ __forceinline__ bf16x8 repack(unsigned p00, unsigned p01,
                                                unsigned p10, unsigned p11,
                                                int src0, int src1, bool hi) {
    union { bf16x8 v; unsigned u[4]; } t;
    unsigned a0, a1;
    a0 = __shfl((int)p00, src0, 64); a1 = __shfl((int)p10, src0, 64); t.u[0] = hi ? a1 : a0;
    a0 = __shfl((int)p01, src0, 64); a1 = __shfl((int)p11, src0, 64); t.u[1] = hi ? a1 : a0;
    a0 = __shfl((int)p00, src1, 64); a1 = __shfl((int)p10, src1, 64); t.u[2] = hi ? a1 : a0;
    a0 = __shfl((int)p01, src1, 64); a1 = __shfl((int)p11, src1, 64); t.u[3] = hi ? a1 : a0;
    return t.v;
}

// ---- weight pre-swizzle: per-tile fragments = A-frags of W^T (== B-frags of W) ----
// q-tiles (fid < 32) are pre-scaled by SCALE.
__global__ void prep_w(const float* __restrict__ qkv_w,
                       const float* __restrict__ proj_w,
                       short* __restrict__ wb) {
    const int fid = blockIdx.x;     // 0..127 (96 qkv + 32 proj)
    const int l   = threadIdx.x;    // 0..63
    const int lq = l & 15, lg = l >> 4;
    bf16x8 v;
    if (fid < 96) {
        const int nt = fid >> 2, kk = fid & 3;
        const float s = (fid < 32) ? SCALE : 1.0f;
        #pragma unroll
        for (int j = 0; j < 8; ++j)
            v[j] = bf1(qkv_w[(kk*32 + lg*8 + j)*384 + nt*16 + lq] * s);
        *(bf16x8*)(wb + fid*512 + l*8) = v;
    } else {
        const int f2 = fid - 96;
        const int nt = f2 >> 2, kk = f2 & 3;
        #pragma unroll
        for (int j = 0; j < 8; ++j)
            v[j] = bf1(proj_w[(kk*32 + lg*8 + j)*128 + nt*16 + lq]);
        *(bf16x8*)(wb + PROJ_WOFF + f2*512 + l*8) = v;
    }
}

// ---- bias+mask pre-pack: bm[win][wave][nt*4+r][lane] as u64 (two bf16x2 words) ----
__global__ void prep_bm(const float* __restrict__ mask,
                        const float* __restrict__ bias_table,
                        ull* __restrict__ bm) {
    const int win = blockIdx.x;        // 0..255
    const int tid = threadIdx.x;       // 256
    const int l = tid & 63, wave = tid >> 6;
    const int lq = l & 15, lg = l >> 4;
    const int qtok = wave*16 + lq;
    const float* mwin = mask + (size_t)win * (NTOK * NTOK);
    const unsigned NEG = pk2(-1e30f, -1e30f);
    ull* dst = bm + (((size_t)win*4 + wave)*16)*64 + l;
    #pragma unroll
    for (int nt = 0; nt < 4; ++nt)
        #pragma unroll
        for (int r = 0; r < 4; ++r) {
            unsigned w0 = NEG, w1 = NEG;
            const int kt = nt*16 + lg*4 + r;
            if (qtok < NTOK && kt < NTOK) {
                const int ridx = (qtok/7 - kt/7 + 6)*13 + (qtok%7 - kt%7 + 6);
                const f32x4 b4 = *(const f32x4*)(bias_table + ridx*4);
                const float mv = mwin[qtok*NTOK + kt];
                w0 = pk2(b4[0] + mv, b4[1] + mv);
                w1 = pk2(b4[2] + mv, b4[3] + mv);
            }
            dst[(nt*4 + r)*64] = (ull)w0 | ((ull)w1 << 32);
        }
}

__global__ __launch_bounds__(256, 4)
void win_attn(const float* __restrict__ x,
              const float* __restrict__ mask,
              const float* __restrict__ qkv_b,
              const float* __restrict__ proj_b,
              const float* __restrict__ bias_table,
              const short* __restrict__ wb,
              const ull* __restrict__ bmt,     // may be null -> fallback gather
              float* __restrict__ out) {
    // kl/vt unpadded, XOR-swizzled in 16B units; wls = 2 x 4KB DMA double-buffer.
    __shared__ __align__(16) short kl[64 * 128];    // k            (16384 B)
    __shared__ __align__(16) short vt[128 * 64];    // v transposed (16384 B)
    __shared__ __align__(16) short wls[4096];       // 2 x 2048-short halves (8192 B)

    const int b    = blockIdx.x;
    const int tid  = threadIdx.x;
    const int l    = tid & 63;
    const int wave = tid >> 6;
    const int lq   = l & 15, lg = l >> 4;
    const int m0   = wave * 16;
    const int qtok = m0 + lq;

    // ---- Phase 1 prologue: DMA tile 0 into buf0 ----
    gll16(wb + tid*8, wls + wave*512);

    // ---- Phase 0: own-stripe x^T B-frags, global -> regs (bf16). Row-clamp pads. ----
    const float* xb = x + (size_t)b * (NTOK * CDIM);
    bf16x8 xa[4];
    {
        int row = qtok; if (row > 48) row = 48;
        const float* pr = xb + row*CDIM + lg*8;
        #pragma unroll
        for (int kk = 0; kk < 4; ++kk) {
            float4 f0 = *(const float4*)(pr + kk*32);
            float4 f1 = *(const float4*)(pr + kk*32 + 4);
            union { bf16x8 v; unsigned u[4]; } t;
            t.u[0] = pk2(f0.x, f0.y);
            t.u[1] = pk2(f0.z, f0.w);
            t.u[2] = pk2(f1.x, f1.y);
            t.u[3] = pk2(f1.z, f1.w);
            xa[kk] = t.v;
        }
    }
    __syncthreads();   // tile 0 staged (x-load latency doubled as cover)

    // ---- Phase 1: 24 wcol-tiles, 1-tile DMA double-buffer pipeline.
    //      q->regs, k/v->swizzled LDS. ----
    unsigned qpk[8][2];   // qpk[nt][w]: q[qtok][nt*16+lg*4+{2w,2w+1}] (pre-scaled)
    #pragma unroll
    for (int nt = 0; nt < 24; ++nt) {
        short* cur = wls + ((nt & 1) ? 2048 : 0);
        if (nt < 23) {   // DMA next tile into the OTHER half (covered by this tile's compute)
            short* oth = wls + ((nt & 1) ? 0 : 2048);
            gll16(wb + (nt + 1)*2048 + tid*8, oth + wave*512);
        }
        bf16x8 wf[4];
        #pragma unroll
        for (int kk = 0; kk < 4; ++kk)
            wf[kk] = *(const bf16x8*)(cur + kk*512 + l*8);
        f32x4 acc = *(const f32x4*)(qkv_b + nt*16 + lg*4);
        if (nt < 8) acc = acc * SCALE;           // weights pre-scaled; scale bias too
        #pragma unroll
        for (int kk = 0; kk < 4; ++kk)
            acc = __builtin_amdgcn_mfma_f32_16x16x32_bf16(wf[kk], xa[kk], acc, 0, 0, 0);
        // D: lane holds (wcol = nt*16+lg*4+r, tok = qtok)
        if (nt < 8) {                            // q -> registers
            qpk[nt][0] = pk2(acc[0], acc[1]);
            qpk[nt][1] = pk2(acc[2], acc[3]);
        } else if (nt < 16) {                    // k -> kl swizzled b64
            unsigned w0 = pk2(acc[0], acc[1]);
            unsigned w1 = pk2(acc[2], acc[3]);
            const int ub  = (nt - 8)*2 + (lg >> 1);
            const int off = qtok*128 + ((ub ^ (qtok & 7)) << 3) + (lg & 1)*4;
            *(ull*)(kl + off) = (ull)w0 | ((ull)w1 << 32);
        } else {                                 // v -> vt[dim][tok] swizzled b16
            #pragma unroll
            for (int r = 0; r < 4; ++r) {
                const int dim = (nt - 16)*16 + lg*4 + r;
                vt[dim*64 + (((qtok >> 3) ^ (dim & 7)) << 3) + (qtok & 7)] = bf1(acc[r]);
            }
        }
        __syncthreads();   // lands next tile's DMA; read-done for cur; kl/vt-ready at nt=23
    }

    // ---- Phase 1c: bias+mask -> bmpk (coalesced table; gather fallback) ----
    unsigned bmpk[4][4][2];
    if (bmt) {
        const ull* src = bmt + ((((size_t)(b & (NWIN-1)))*4 + wave)*16)*64 + l;
        #pragma unroll
        for (int nt = 0; nt < 4; ++nt)
            #pragma unroll
            for (int r = 0; r < 4; ++r) {
                const ull u = src[(nt*4 + r)*64];
                bmpk[nt][r][0] = (unsigned)u;
                bmpk[nt][r][1] = (unsigned)(u >> 32);
            }
    } else {
        const float* mwin = mask + (size_t)(b & (NWIN - 1)) * (NTOK * NTOK);
        const unsigned NEG = pk2(-1e30f, -1e30f);
        #pragma unroll
        for (int nt = 0; nt < 4; ++nt)
            #pragma unroll
            for (int r = 0; r < 4; ++r) {
                const int kt = nt*16 + lg*4 + r;
                if (qtok < NTOK && kt < NTOK) {
                    const int ridx = (qtok/7 - kt/7 + 6)*13 + (qtok%7 - kt%7 + 6);
                    const f32x4 b4 = *(const f32x4*)(bias_table + ridx*4);
                    const float mv = mwin[qtok*NTOK + kt];
                    bmpk[nt][r][0] = pk2(b4[0] + mv, b4[1] + mv);
                    bmpk[nt][r][1] = pk2(b4[2] + mv, b4[3] + mv);
                } else {
                    bmpk[nt][r][0] = NEG; bmpk[nt][r][1] = NEG;
                }
            }
    }

    // ---- Phase-3 tile-0 DMA issued NOW: covered by the whole of phase 2.
    //      (wls untouched during phase 2; last readers finished at the final
    //       phase-1 barrier.) ----
    gll16(wb + PROJ_WOFF + tid*8, wls + wave*512);

    // ---- Phase 2: attention in HEAD PAIRS (two independent chains).
    //      Softmax WITHOUT max-subtraction (proven R16/R17). ----
    const int src0 = lq + 16*((2*lg + 0) & 3);       // repack source lanes
    const int src1 = lq + 16*((2*lg + 1) & 3);
    const bool hi  = (lg >> 1);
    unsigned aopk[8][2];                             // ao[qtok][tile*16+lg*4+{..}], tile=2h+dn

    #pragma unroll
    for (int hp = 0; hp < 2; ++hp) {
        const int h0 = 2*hp, h1 = h0 + 1;
        const bf16x8 qfA = repack(qpk[2*h0][0], qpk[2*h0][1], qpk[2*h0+1][0], qpk[2*h0+1][1],
                                  src0, src1, hi);
        const bf16x8 qfB = repack(qpk[2*h1][0], qpk[2*h1][1], qpk[2*h1+1][0], qpk[2*h1+1][1],
                                  src0, src1, hi);
        // S^T tiles for both heads: D[ktok][qtok] = K(A) . Q^T(B)
        f32x4 sA[4], sB[4];
        __builtin_amdgcn_s_setprio(1);
        #pragma unroll
        for (int nt = 0; nt < 4; ++nt) {
            const int krow = nt*16 + lq;
            bf16x8 kfA = *(const bf16x8*)(kl + krow*128 + (((h0*4 + lg) ^ (krow & 7)) << 3));
            bf16x8 kfB = *(const bf16x8*)(kl + krow*128 + (((h1*4 + lg) ^ (krow & 7)) << 3));
            f32x4 z = {0.f, 0.f, 0.f, 0.f};
            sA[nt] = __builtin_amdgcn_mfma_f32_16x16x32_bf16(kfA, qfA, z, 0, 0, 0);
            sB[nt] = __builtin_amdgcn_mfma_f32_16x16x32_bf16(kfB, qfB, z, 0, 0, 0);
        }
        __builtin_amdgcn_s_setprio(0);
        // + bias+mask: head h0 = low short of word hp, h1 = high short
        #pragma unroll
        for (int nt = 0; nt < 4; ++nt)
            #pragma unroll
            for (int r = 0; r < 4; ++r) {
                const unsigned u = bmpk[nt][r][hp];
                sA[nt][r] += __uint_as_float(u << 16);
                sB[nt][r] += __uint_as_float(u & 0xffff0000u);
            }
        // softmax (no max-sub): exp directly, tree-sum, 2 shfl, reciprocal
        float sumA, sumB;
        {
            float a_[4], b_[4];
            #pragma unroll
            for (int nt = 0; nt < 4; ++nt) {
                #pragma unroll
                for (int r = 0; r < 4; ++r) {
                    sA[nt][r] = __expf(sA[nt][r]);
                    sB[nt][r] = __expf(sB[nt][r]);
                }
                a_[nt] = (sA[nt][0] + sA[nt][1]) + (sA[nt][2] + sA[nt][3]);
                b_[nt] = (sB[nt][0] + sB[nt][1]) + (sB[nt][2] + sB[nt][3]);
            }
            sumA = (a_[0] + a_[1]) + (a_[2] + a_[3]);
            sumB = (b_[0] + b_[1]) + (b_[2] + b_[3]);
        }
        sumA += __shfl_xor(sumA, 16, 64);
        sumB += __shfl_xor(sumB, 16, 64);
        sumA += __shfl_xor(sumA, 32, 64);
        sumB += __shfl_xor(sumB, 32, 64);
        const float invA = 1.0f / sumA;
        const float invB = 1.0f / sumB;
        // normalize + pack + repack to P^T B-frags, both heads
        unsigned pkvA[4][2], pkvB[4][2];
        #pragma unroll
        for (int nt = 0; nt < 4; ++nt) {
            pkvA[nt][0] = pk2(sA[nt][0]*invA, sA[nt][1]*invA);
            pkvA[nt][1] = pk2(sA[nt][2]*invA, sA[nt][3]*invA);
            pkvB[nt][0] = pk2(sB[nt][0]*invB, sB[nt][1]*invB);
            pkvB[nt][1] = pk2(sB[nt][2]*invB, sB[nt][3]*invB);
        }
        bf16x8 paA[2], paB[2];
        #pragma unroll
        for (int c = 0; c < 2; ++c) {
            paA[c] = repack(pkvA[2*c][0], pkvA[2*c][1], pkvA[2*c+1][0], pkvA[2*c+1][1],
                            src0, src1, hi);
            paB[c] = repack(pkvB[2*c][0], pkvB[2*c][1], pkvB[2*c+1][0], pkvB[2*c+1][1],
                            src0, src1, hi);
        }
        // PV both heads: ao^T = V^T(A) . P^T(B)
        #pragma unroll
        for (int dn = 0; dn < 2; ++dn) {
            f32x4 oA = {0.f, 0.f, 0.f, 0.f};
            f32x4 oB = {0.f, 0.f, 0.f, 0.f};
            __builtin_amdgcn_s_setprio(1);
            #pragma unroll
            for (int kk = 0; kk < 2; ++kk) {
                const int dimA = h0*32 + dn*16 + lq;
                const int dimB = h1*32 + dn*16 + lq;
                bf16x8 vfA = *(const bf16x8*)(vt + dimA*64 + (((kk*4 + lg) ^ (dimA & 7)) << 3));
                bf16x8 vfB = *(const bf16x8*)(vt + dimB*64 + (((kk*4 + lg) ^ (dimB & 7)) << 3));
                oA = __builtin_amdgcn_mfma_f32_16x16x32_bf16(vfA, paA[kk], oA, 0, 0, 0);
                oB = __builtin_amdgcn_mfma_f32_16x16x32_bf16(vfB, paB[kk], oB, 0, 0, 0);
            }
            __builtin_amdgcn_s_setprio(0);
            aopk[2*h0 + dn][0] = pk2(oA[0], oA[1]);
            aopk[2*h0 + dn][1] = pk2(oA[2], oA[3]);
            aopk[2*h1 + dn][0] = pk2(oB[0], oB[1]);
            aopk[2*h1 + dn][1] = pk2(oB[2], oB[3]);
        }
    }

    // ---- Phase 3: out^T = Wp^T(A) . ao^T(B); proj weights via DMA dbuf. ----
    bf16x8 ab[4];
    #pragma unroll
    for (int kk = 0; kk < 4; ++kk)
        ab[kk] = repack(aopk[2*kk][0], aopk[2*kk][1], aopk[2*kk+1][0], aopk[2*kk+1][1],
                        src0, src1, hi);
    float* ob = out + (size_t)b * (NTOK * CDIM);
    __syncthreads();   // proj tile 0 landed (all waves' DMA drained)
    #pragma unroll
    for (int nt = 0; nt < 8; ++nt) {
        short* cur = wls + ((nt & 1) ? 2048 : 0);
        if (nt < 7) {   // DMA next proj tile into the OTHER half
            short* oth = wls + ((nt & 1) ? 0 : 2048);
            gll16(wb + PROJ_WOFF + (nt + 1)*2048 + tid*8, oth + wave*512);
        }
        bf16x8 wf[4];
        #pragma unroll
        for (int kk = 0; kk < 4; ++kk)
            wf[kk] = *(const bf16x8*)(cur + kk*512 + l*8);
        f32x4 acc = *(const f32x4*)(proj_b + nt*16 + lg*4);    // D rows = ocols
        #pragma unroll
        for (int kk = 0; kk < 4; ++kk)
            acc = __builtin_amdgcn_mfma_f32_16x16x32_bf16(wf[kk], ab[kk], acc, 0, 0, 0);
        // D: (ocol = nt*16+lg*4+r, tok = qtok) -> out[tok][ocol], f32x4 store
        if (qtok < NTOK)
            *(f32x4*)(ob + qtok*CDIM + nt*16 + lg*4) = acc;
        if (nt < 7) __syncthreads();   // lands next tile; read-done for cur
    }
}

extern "C" void kernel_launch(void* const* d_in, const int* in_sizes, int n_in,
                              void* d_out, int out_size, void* d_ws, size_t ws_size,
                              hipStream_t stream) {
    (void)in_sizes; (void)n_in; (void)out_size;
    const float* x          = (const float*)d_in[0];
    const float* mask       = (const float*)d_in[1];
    const float* qkv_w      = (const float*)d_in[2];
    const float* qkv_b      = (const float*)d_in[3];
    const float* proj_w     = (const float*)d_in[4];
    const float* proj_b     = (const float*)d_in[5];
    const float* bias_table = (const float*)d_in[6];
    float* out = (float*)d_out;
    short* wb  = (short*)d_ws;                       // first 131072 B

    const size_t bm_bytes = (size_t)NWIN * 4 * 16 * 64 * 8;   // 8,388,608
    ull* bmt = nullptr;
    if (ws_size >= (size_t)WB_BYTES + bm_bytes)
        bmt = (ull*)((char*)d_ws + WB_BYTES);

    hipLaunchKernelGGL(prep_w, dim3(128), dim3(64), 0, stream, qkv_w, proj_w, wb);
    if (bmt)
        hipLaunchKernelGGL(prep_bm, dim3(NWIN), dim3(256), 0, stream, mask, bias_table, bmt);
    hipLaunchKernelGGL(win_attn, dim3(4096), dim3(256), 0, stream,
                       x, mask, qkv_b, proj_b, bias_table, wb, bmt, out);
}

// Round 20
// 115.014 us; speedup vs baseline: 1.0997x; 1.0997x over previous
//
#include <hip/hip_runtime.h>
#include <hip/hip_bf16.h>

// Swin window attention, fully fused, bf16-MFMA.
// Base = round-18 (best: 117.1 us): R14 structure + weight de-dup through LDS.
// (R19's global_load_lds dbuf REGRESSED: per-tile __syncthreads drains
// vmcnt(0) -> kills the DMA prefetch; the m97 structural stall. Reverted.)
// Round-20 single change: T14 depth-2 REGISTER staging pipeline for the
// weight de-dup. Regs are not drained by barriers, so the prefetch survives:
//   per tile nt: (A) issue global load of tile nt+2 into the freed named reg
//   set (rE/rO parity, full unroll); (B) compute tile nt from LDS half nt&1;
//   (C) ds_write tile nt+1 (issued a full tile ago -> latency covered);
//   (D) one barrier. 25 barriers ~= R18's 24; 4 blocks/CU unchanged.
// Phase 3: same depth-2 (loads issued before ab-repack, which covers them).
// MFMA 16x16x32 bf16 layouts (validated end-to-end rounds 3/5/6/8):
//   src0 A: lane holds A[lane&15][(lane>>4)*8+j]
//   src1 B: lane holds B[(lane>>4)*8+j][lane&15]
//   D:      lane holds D[(lane>>4)*4+r][lane&15]

typedef __attribute__((ext_vector_type(8))) short bf16x8;
typedef __attribute__((ext_vector_type(4))) float f32x4;
typedef unsigned long long ull;

#define NTOK  49
#define CDIM  128
#define NWIN  256
#define SCALE 0.17677669529663687f
#define PROJ_WOFF 49152            // shorts: 96 frags * 512
#define WB_BYTES  131072

static __device__ __forceinline__ unsigned pk2(float a, float b) {
    __hip_bfloat162 h = __float22bfloat162_rn(make_float2(a, b));  // low = a, high = b, RNE
    unsigned u; __builtin_memcpy(&u, &h, 4); return u;
}
static __device__ __forceinline__ short bf1(float a) {
    __hip_bfloat16 h = __float2bfloat16(a);
    unsigned short u; __builtin_memcpy(&u, &h, 2); return (short)u;
}
static __device__ __forceinline__ bf16x8 repack(unsigned p00, unsigned p01,
                                                unsigned p10, unsigned p11,
                                                int src0, int src1, bool hi) {
    union { bf16x8 v; unsigned u[4]; } t;
    unsigned a0, a1;
    a0 = __shfl((int)p00, src0, 64); a1 = __shfl((int)p10, src0, 64); t.u[0] = hi ? a1 : a0;
    a0 = __shfl((int)p01, src0, 64); a1 = __shfl((int)p11, src0, 64); t.u[1] = hi ? a1 : a0;
    a0 = __shfl((int)p00, src1, 64); a1 = __shfl((int)p10, src1, 64); t.u[2] = hi ? a1 : a0;
    a0 = __shfl((int)p01, src1, 64); a1 = __shfl((int)p11, src1, 64); t.u[3] = hi ? a1 : a0;
    return t.v;
}

// ---- weight pre-swizzle: per-tile fragments = A-frags of W^T (== B-frags of W) ----
// q-tiles (fid < 32) are pre-scaled by SCALE.
__global__ void prep_w(const float* __restrict__ qkv_w,
                       const float* __restrict__ proj_w,
                       short* __restrict__ wb) {
    const int fid = blockIdx.x;     // 0..127 (96 qkv + 32 proj)
    const int l   = threadIdx.x;    // 0..63
    const int lq = l & 15, lg = l >> 4;
    bf16x8 v;
    if (fid < 96) {
        const int nt = fid >> 2, kk = fid & 3;
        const float s = (fid < 32) ? SCALE : 1.0f;
        #pragma unroll
        for (int j = 0; j < 8; ++j)
            v[j] = bf1(qkv_w[(kk*32 + lg*8 + j)*384 + nt*16 + lq] * s);
        *(bf16x8*)(wb + fid*512 + l*8) = v;
    } else {
        const int f2 = fid - 96;
        const int nt = f2 >> 2, kk = f2 & 3;
        #pragma unroll
        for (int j = 0; j < 8; ++j)
            v[j] = bf1(proj_w[(kk*32 + lg*8 + j)*128 + nt*16 + lq]);
        *(bf16x8*)(wb + PROJ_WOFF + f2*512 + l*8) = v;
    }
}

// ---- bias+mask pre-pack: bm[win][wave][nt*4+r][lane] as u64 (two bf16x2 words) ----
__global__ void prep_bm(const float* __restrict__ mask,
                        const float* __restrict__ bias_table,
                        ull* __restrict__ bm) {
    const int win = blockIdx.x;        // 0..255
    const int tid = threadIdx.x;       // 256
    const int l = tid & 63, wave = tid >> 6;
    const int lq = l & 15, lg = l >> 4;
    const int qtok = wave*16 + lq;
    const float* mwin = mask + (size_t)win * (NTOK * NTOK);
    const unsigned NEG = pk2(-1e30f, -1e30f);
    ull* dst = bm + (((size_t)win*4 + wave)*16)*64 + l;
    #pragma unroll
    for (int nt = 0; nt < 4; ++nt)
        #pragma unroll
        for (int r = 0; r < 4; ++r) {
            unsigned w0 = NEG, w1 = NEG;
            const int kt = nt*16 + lg*4 + r;
            if (qtok < NTOK && kt < NTOK) {
                const int ridx = (qtok/7 - kt/7 + 6)*13 + (qtok%7 - kt%7 + 6);
                const f32x4 b4 = *(const f32x4*)(bias_table + ridx*4);
                const float mv = mwin[qtok*NTOK + kt];
                w0 = pk2(b4[0] + mv, b4[1] + mv);
                w1 = pk2(b4[2] + mv, b4[3] + mv);
            }
            dst[(nt*4 + r)*64] = (ull)w0 | ((ull)w1 << 32);
        }
}

__global__ __launch_bounds__(256, 4)
void win_attn(const float* __restrict__ x,
              const float* __restrict__ mask,
              const float* __restrict__ qkv_b,
              const float* __restrict__ proj_b,
              const float* __restrict__ bias_table,
              const short* __restrict__ wb,
              const ull* __restrict__ bmt,     // may be null -> fallback gather
              float* __restrict__ out) {
    // kl/vt unpadded, XOR-swizzled in 16B units; wls = 2 x 4KB tile dbuf halves.
    __shared__ __align__(16) short kl[64 * 128];    // k            (16384 B)
    __shared__ __align__(16) short vt[128 * 64];    // v transposed (16384 B)
    __shared__ __align__(16) short wls[4096];       // halves: [0,2048) / [2048,4096)

    const int b    = blockIdx.x;
    const int tid  = threadIdx.x;
    const int l    = tid & 63;
    const int wave = tid >> 6;
    const int lq   = l & 15, lg = l >> 4;
    const int m0   = wave * 16;
    const int qtok = m0 + lq;

    // ---- Phase 1 prologue: issue tiles 0,1 into named reg sets ----
    bf16x8 rE = *(const bf16x8*)(wb + 0*2048 + tid*8);   // even tiles
    bf16x8 rO = *(const bf16x8*)(wb + 1*2048 + tid*8);   // odd tiles

    // ---- Phase 0: own-stripe x^T B-frags, global -> regs (bf16). Row-clamp pads.
    //      (covers the prologue load latency) ----
    const float* xb = x + (size_t)b * (NTOK * CDIM);
    bf16x8 xa[4];
    {
        int row = qtok; if (row > 48) row = 48;
        const float* pr = xb + row*CDIM + lg*8;
        #pragma unroll
        for (int kk = 0; kk < 4; ++kk) {
            float4 f0 = *(const float4*)(pr + kk*32);
            float4 f1 = *(const float4*)(pr + kk*32 + 4);
            union { bf16x8 v; unsigned u[4]; } t;
            t.u[0] = pk2(f0.x, f0.y);
            t.u[1] = pk2(f0.z, f0.w);
            t.u[2] = pk2(f1.x, f1.y);
            t.u[3] = pk2(f1.z, f1.w);
            xa[kk] = t.v;
        }
    }
    *(bf16x8*)(wls + tid*8) = rE;   // stage tile 0 into half0
    __syncthreads();                 // tile 0 staged

    // ---- Phase 1: 24 wcol-tiles, depth-2 register pipeline.
    //      q->regs, k/v->swizzled LDS. One barrier per tile. ----
    unsigned qpk[8][2];   // qpk[nt][w]: q[qtok][nt*16+lg*4+{2w,2w+1}] (pre-scaled)
    #pragma unroll
    for (int nt = 0; nt < 24; ++nt) {
        short* cur = wls + ((nt & 1) ? 2048 : 0);
        short* oth = wls + ((nt & 1) ? 0 : 2048);
        // (A) issue load of tile nt+2 into the freed set (parity nt&1)
        if (nt + 2 < 24) {
            if ((nt & 1) == 0) rE = *(const bf16x8*)(wb + (nt + 2)*2048 + tid*8);
            else               rO = *(const bf16x8*)(wb + (nt + 2)*2048 + tid*8);
        }
        // (B) compute tile nt from cur
        bf16x8 wf[4];
        #pragma unroll
        for (int kk = 0; kk < 4; ++kk)
            wf[kk] = *(const bf16x8*)(cur + kk*512 + l*8);
        f32x4 acc = *(const f32x4*)(qkv_b + nt*16 + lg*4);
        if (nt < 8) acc = acc * SCALE;           // weights pre-scaled; scale bias too
        #pragma unroll
        for (int kk = 0; kk < 4; ++kk)
            acc = __builtin_amdgcn_mfma_f32_16x16x32_bf16(wf[kk], xa[kk], acc, 0, 0, 0);
        // D: lane holds (wcol = nt*16+lg*4+r, tok = qtok)
        if (nt < 8) {                            // q -> registers
            qpk[nt][0] = pk2(acc[0], acc[1]);
            qpk[nt][1] = pk2(acc[2], acc[3]);
        } else if (nt < 16) {                    // k -> kl swizzled b64
            unsigned w0 = pk2(acc[0], acc[1]);
            unsigned w1 = pk2(acc[2], acc[3]);
            const int ub  = (nt - 8)*2 + (lg >> 1);
            const int off = qtok*128 + ((ub ^ (qtok & 7)) << 3) + (lg & 1)*4;
            *(ull*)(kl + off) = (ull)w0 | ((ull)w1 << 32);
        } else {                                 // v -> vt[dim][tok] swizzled b16
            #pragma unroll
            for (int r = 0; r < 4; ++r) {
                const int dim = (nt - 16)*16 + lg*4 + r;
                vt[dim*64 + (((qtok >> 3) ^ (dim & 7)) << 3) + (qtok & 7)] = bf1(acc[r]);
            }
        }
        // (C) write tile nt+1 (loaded a full tile ago) into the other half
        if (nt + 1 < 24)
            *(bf16x8*)(oth + tid*8) = ((nt & 1) == 0) ? rO : rE;
        // (D) barrier: oth staged for nt+1; cur read-done; kl/vt-ready at nt=23
        __syncthreads();
    }

    // ---- Phase 1c: bias+mask -> bmpk (coalesced table; gather fallback) ----
    unsigned bmpk[4][4][2];
    if (bmt) {
        const ull* src = bmt + ((((size_t)(b & (NWIN-1)))*4 + wave)*16)*64 + l;
        #pragma unroll
        for (int nt = 0; nt < 4; ++nt)
            #pragma unroll
            for (int r = 0; r < 4; ++r) {
                const ull u = src[(nt*4 + r)*64];
                bmpk[nt][r][0] = (unsigned)u;
                bmpk[nt][r][1] = (unsigned)(u >> 32);
            }
    } else {
        const float* mwin = mask + (size_t)(b & (NWIN - 1)) * (NTOK * NTOK);
        const unsigned NEG = pk2(-1e30f, -1e30f);
        #pragma unroll
        for (int nt = 0; nt < 4; ++nt)
            #pragma unroll
            for (int r = 0; r < 4; ++r) {
                const int kt = nt*16 + lg*4 + r;
                if (qtok < NTOK && kt < NTOK) {
                    const int ridx = (qtok/7 - kt/7 + 6)*13 + (qtok%7 - kt%7 + 6);
                    const f32x4 b4 = *(const f32x4*)(bias_table + ridx*4);
                    const float mv = mwin[qtok*NTOK + kt];
                    bmpk[nt][r][0] = pk2(b4[0] + mv, b4[1] + mv);
                    bmpk[nt][r][1] = pk2(b4[2] + mv, b4[3] + mv);
                } else {
                    bmpk[nt][r][0] = NEG; bmpk[nt][r][1] = NEG;
                }
            }
    }

    // ---- Phase 2: attention in HEAD PAIRS (two independent chains).
    //      Softmax WITHOUT max-subtraction (proven R16/R17). ----
    const int src0 = lq + 16*((2*lg + 0) & 3);       // repack source lanes
    const int src1 = lq + 16*((2*lg + 1) & 3);
    const bool hi  = (lg >> 1);
    unsigned aopk[8][2];                             // ao[qtok][tile*16+lg*4+{..}], tile=2h+dn

    #pragma unroll
    for (int hp = 0; hp < 2; ++hp) {
        const int h0 = 2*hp, h1 = h0 + 1;
        const bf16x8 qfA = repack(qpk[2*h0][0], qpk[2*h0][1], qpk[2*h0+1][0], qpk[2*h0+1][1],
                                  src0, src1, hi);
        const bf16x8 qfB = repack(qpk[2*h1][0], qpk[2*h1][1], qpk[2*h1+1][0], qpk[2*h1+1][1],
                                  src0, src1, hi);
        // S^T tiles for both heads: D[ktok][qtok] = K(A) . Q^T(B)
        f32x4 sA[4], sB[4];
        __builtin_amdgcn_s_setprio(1);
        #pragma unroll
        for (int nt = 0; nt < 4; ++nt) {
            const int krow = nt*16 + lq;
            bf16x8 kfA = *(const bf16x8*)(kl + krow*128 + (((h0*4 + lg) ^ (krow & 7)) << 3));
            bf16x8 kfB = *(const bf16x8*)(kl + krow*128 + (((h1*4 + lg) ^ (krow & 7)) << 3));
            f32x4 z = {0.f, 0.f, 0.f, 0.f};
            sA[nt] = __builtin_amdgcn_mfma_f32_16x16x32_bf16(kfA, qfA, z, 0, 0, 0);
            sB[nt] = __builtin_amdgcn_mfma_f32_16x16x32_bf16(kfB, qfB, z, 0, 0, 0);
        }
        __builtin_amdgcn_s_setprio(0);
        // + bias+mask: head h0 = low short of word hp, h1 = high short
        #pragma unroll
        for (int nt = 0; nt < 4; ++nt)
            #pragma unroll
            for (int r = 0; r < 4; ++r) {
                const unsigned u = bmpk[nt][r][hp];
                sA[nt][r] += __uint_as_float(u << 16);
                sB[nt][r] += __uint_as_float(u & 0xffff0000u);
            }
        // softmax (no max-sub): exp directly, tree-sum, 2 shfl, reciprocal
        float sumA, sumB;
        {
            float a_[4], b_[4];
            #pragma unroll
            for (int nt = 0; nt < 4; ++nt) {
                #pragma unroll
                for (int r = 0; r < 4; ++r) {
                    sA[nt][r] = __expf(sA[nt][r]);
                    sB[nt][r] = __expf(sB[nt][r]);
                }
                a_[nt] = (sA[nt][0] + sA[nt][1]) + (sA[nt][2] + sA[nt][3]);
                b_[nt] = (sB[nt][0] + sB[nt][1]) + (sB[nt][2] + sB[nt][3]);
            }
            sumA = (a_[0] + a_[1]) + (a_[2] + a_[3]);
            sumB = (b_[0] + b_[1]) + (b_[2] + b_[3]);
        }
        sumA += __shfl_xor(sumA, 16, 64);
        sumB += __shfl_xor(sumB, 16, 64);
        sumA += __shfl_xor(sumA, 32, 64);
        sumB += __shfl_xor(sumB, 32, 64);
        const float invA = 1.0f / sumA;
        const float invB = 1.0f / sumB;
        // normalize + pack + repack to P^T B-frags, both heads
        unsigned pkvA[4][2], pkvB[4][2];
        #pragma unroll
        for (int nt = 0; nt < 4; ++nt) {
            pkvA[nt][0] = pk2(sA[nt][0]*invA, sA[nt][1]*invA);
            pkvA[nt][1] = pk2(sA[nt][2]*invA, sA[nt][3]*invA);
            pkvB[nt][0] = pk2(sB[nt][0]*invB, sB[nt][1]*invB);
            pkvB[nt][1] = pk2(sB[nt][2]*invB, sB[nt][3]*invB);
        }
        bf16x8 paA[2], paB[2];
        #pragma unroll
        for (int c = 0; c < 2; ++c) {
            paA[c] = repack(pkvA[2*c][0], pkvA[2*c][1], pkvA[2*c+1][0], pkvA[2*c+1][1],
                            src0, src1, hi);
            paB[c] = repack(pkvB[2*c][0], pkvB[2*c][1], pkvB[2*c+1][0], pkvB[2*c+1][1],
                            src0, src1, hi);
        }
        // PV both heads: ao^T = V^T(A) . P^T(B)
        #pragma unroll
        for (int dn = 0; dn < 2; ++dn) {
            f32x4 oA = {0.f, 0.f, 0.f, 0.f};
            f32x4 oB = {0.f, 0.f, 0.f, 0.f};
            __builtin_amdgcn_s_setprio(1);
            #pragma unroll
            for (int kk = 0; kk < 2; ++kk) {
                const int dimA = h0*32 + dn*16 + lq;
                const int dimB = h1*32 + dn*16 + lq;
                bf16x8 vfA = *(const bf16x8*)(vt + dimA*64 + (((kk*4 + lg) ^ (dimA & 7)) << 3));
                bf16x8 vfB = *(const bf16x8*)(vt + dimB*64 + (((kk*4 + lg) ^ (dimB & 7)) << 3));
                oA = __builtin_amdgcn_mfma_f32_16x16x32_bf16(vfA, paA[kk], oA, 0, 0, 0);
                oB = __builtin_amdgcn_mfma_f32_16x16x32_bf16(vfB, paB[kk], oB, 0, 0, 0);
            }
            __builtin_amdgcn_s_setprio(0);
            aopk[2*h0 + dn][0] = pk2(oA[0], oA[1]);
            aopk[2*h0 + dn][1] = pk2(oA[2], oA[3]);
            aopk[2*h1 + dn][0] = pk2(oB[0], oB[1]);
            aopk[2*h1 + dn][1] = pk2(oB[2], oB[3]);
        }
    }

    // ---- Phase 3: out^T = Wp^T(A) . ao^T(B); depth-2 register pipeline.
    //      Tile-0/1 loads issued BEFORE the ab repack (repack covers them). ----
    bf16x8 pE = *(const bf16x8*)(wb + PROJ_WOFF + 0*2048 + tid*8);
    bf16x8 pO = *(const bf16x8*)(wb + PROJ_WOFF + 1*2048 + tid*8);
    bf16x8 ab[4];
    #pragma unroll
    for (int kk = 0; kk < 4; ++kk)
        ab[kk] = repack(aopk[2*kk][0], aopk[2*kk][1], aopk[2*kk+1][0], aopk[2*kk+1][1],
                        src0, src1, hi);
    float* ob = out + (size_t)b * (NTOK * CDIM);
    // wls free: last readers finished at the final phase-1 barrier.
    *(bf16x8*)(wls + tid*8) = pE;   // stage proj tile 0 into half0
    __syncthreads();
    #pragma unroll
    for (int nt = 0; nt < 8; ++nt) {
        short* cur = wls + ((nt & 1) ? 2048 : 0);
        short* oth = wls + ((nt & 1) ? 0 : 2048);
        if (nt + 2 < 8) {
            if ((nt & 1) == 0) pE = *(const bf16x8*)(wb + PROJ_WOFF + (nt + 2)*2048 + tid*8);
            else               pO = *(const bf16x8*)(wb + PROJ_WOFF + (nt + 2)*2048 + tid*8);
        }
        bf16x8 wf[4];
        #pragma unroll
        for (int kk = 0; kk < 4; ++kk)
            wf[kk] = *(const bf16x8*)(cur + kk*512 + l*8);
        f32x4 acc = *(const f32x4*)(proj_b + nt*16 + lg*4);    // D rows = ocols
        #pragma unroll
        for (int kk = 0; kk < 4; ++kk)
            acc = __builtin_amdgcn_mfma_f32_16x16x32_bf16(wf[kk], ab[kk], acc, 0, 0, 0);
        // D: (ocol = nt*16+lg*4+r, tok = qtok) -> out[tok][ocol], f32x4 store
        if (qtok < NTOK)
            *(f32x4*)(ob + qtok*CDIM + nt*16 + lg*4) = acc;
        if (nt + 1 < 8)
            *(bf16x8*)(oth + tid*8) = ((nt & 1) == 0) ? pO : pE;
        if (nt < 7) __syncthreads();
    }
}

extern "C" void kernel_launch(void* const* d_in, const int* in_sizes, int n_in,
                              void* d_out, int out_size, void* d_ws, size_t ws_size,
                              hipStream_t stream) {
    (void)in_sizes; (void)n_in; (void)out_size;
    const float* x          = (const float*)d_in[0];
    const float* mask       = (const float*)d_in[1];
    const float* qkv_w      = (const float*)d_in[2];
    const float* qkv_b      = (const float*)d_in[3];
    const float* proj_w     = (const float*)d_in[4];
    const float* proj_b     = (const float*)d_in[5];
    const float* bias_table = (const float*)d_in[6];
    float* out = (float*)d_out;
    short* wb  = (short*)d_ws;                       // first 131072 B

    const size_t bm_bytes = (size_t)NWIN * 4 * 16 * 64 * 8;   // 8,388,608
    ull* bmt = nullptr;
    if (ws_size >= (size_t)WB_BYTES + bm_bytes)
        bmt = (ull*)((char*)d_ws + WB_BYTES);

    hipLaunchKernelGGL(prep_w, dim3(128), dim3(64), 0, stream, qkv_w, proj_w, wb);
    if (bmt)
        hipLaunchKernelGGL(prep_bm, dim3(NWIN), dim3(256), 0, stream, mask, bias_table, bmt);
    hipLaunchKernelGGL(win_attn, dim3(4096), dim3(256), 0, stream,
                       x, mask, qkv_b, proj_b, bias_table, wb, bmt, out);
}